// Round 1
// baseline (471.950 us; speedup 1.0000x reference)
//
#include <hip/hip_runtime.h>
#include <hip/hip_bf16.h>

#define IN_DIM 256
#define HEADS 4
#define HID 64
#define NEG_SLOPE 0.2f

// ---------- helpers: ordered-uint encoding for float atomicMax ----------
__device__ __forceinline__ unsigned flipf(float f) {
    unsigned u = __float_as_uint(f);
    return (u & 0x80000000u) ? ~u : (u | 0x80000000u);
}
__device__ __forceinline__ float unflipf(unsigned u) {
    return __uint_as_float((u & 0x80000000u) ? (u & 0x7fffffffu) : ~u);
}

// ---------- 1. GEMM: feat[N,256] = x[N,256] @ W[256,256] ----------
// 64x64 tile, 256 threads, 4x4 microtile, TK=16.
#define TM 64
#define TN 64
#define TK 16
__global__ __launch_bounds__(256) void gemm_kernel(
        const float* __restrict__ x, const float* __restrict__ W,
        float* __restrict__ feat, int N) {
    __shared__ float As[TK][TM + 4];   // +4 pad: rows stay 16B-aligned (68*4=272)
    __shared__ float Bs[TK][TN];
    const int bm = blockIdx.x * TM;
    const int bn = blockIdx.y * TN;
    const int tid = threadIdx.x;
    const int tr = (tid / 16) * 4;
    const int tc = (tid % 16) * 4;
    float acc[4][4] = {};

    for (int k0 = 0; k0 < IN_DIM; k0 += TK) {
        // load A tile: 64 rows x 16 k, coalesced in k (64B segments)
        #pragma unroll
        for (int i = tid; i < TM * TK; i += 256) {
            int m = i >> 4, k = i & 15;
            int row = bm + m;
            As[k][m] = (row < N) ? x[row * IN_DIM + k0 + k] : 0.f;
        }
        // load B tile: 16 k x 64 n, coalesced in n
        #pragma unroll
        for (int i = tid; i < TK * TN; i += 256) {
            int k = i >> 6, n = i & 63;
            Bs[k][n] = W[(k0 + k) * (HEADS * HID) + bn + n];
        }
        __syncthreads();
        #pragma unroll
        for (int k = 0; k < TK; ++k) {
            float4 a = *(const float4*)&As[k][tr];
            float4 b = *(const float4*)&Bs[k][tc];
            acc[0][0] += a.x * b.x; acc[0][1] += a.x * b.y; acc[0][2] += a.x * b.z; acc[0][3] += a.x * b.w;
            acc[1][0] += a.y * b.x; acc[1][1] += a.y * b.y; acc[1][2] += a.y * b.z; acc[1][3] += a.y * b.w;
            acc[2][0] += a.z * b.x; acc[2][1] += a.z * b.y; acc[2][2] += a.z * b.z; acc[2][3] += a.z * b.w;
            acc[3][0] += a.w * b.x; acc[3][1] += a.w * b.y; acc[3][2] += a.w * b.z; acc[3][3] += a.w * b.w;
        }
        __syncthreads();
    }
    #pragma unroll
    for (int i = 0; i < 4; ++i) {
        int row = bm + tr + i;
        if (row < N) {
            float4 v = make_float4(acc[i][0], acc[i][1], acc[i][2], acc[i][3]);
            *(float4*)&feat[row * (HEADS * HID) + bn + tc] = v;
        }
    }
}

// ---------- 2. el/er: per-node attention logits ----------
// one wave per node; lane l holds feat[n, 4l..4l+3]; head h = l/16
__global__ __launch_bounds__(256) void elr_kernel(
        const float* __restrict__ feat,
        const float* __restrict__ attn_l, const float* __restrict__ attn_r,
        float* __restrict__ el, float* __restrict__ er, int N) {
    int wid = (blockIdx.x * blockDim.x + threadIdx.x) >> 6;
    int lane = threadIdx.x & 63;
    if (wid >= N) return;
    float4 f = ((const float4*)(feat + wid * (HEADS * HID)))[lane];
    int h = lane >> 4;
    float4 al = ((const float4*)(attn_l + h * HID))[lane & 15];
    float4 ar = ((const float4*)(attn_r + h * HID))[lane & 15];
    float pl = f.x * al.x + f.y * al.y + f.z * al.z + f.w * al.w;
    float pr = f.x * ar.x + f.y * ar.y + f.z * ar.z + f.w * ar.w;
    #pragma unroll
    for (int off = 1; off < 16; off <<= 1) {
        pl += __shfl_xor(pl, off);
        pr += __shfl_xor(pr, off);
    }
    if ((lane & 15) == 0) {
        el[wid * HEADS + h] = pl;
        er[wid * HEADS + h] = pr;
    }
}

// ---------- 3. edge scores + segment max ----------
__global__ __launch_bounds__(256) void edge_score_kernel(
        const float* __restrict__ el, const float* __restrict__ er,
        const int* __restrict__ src, const int* __restrict__ dst,
        float* __restrict__ e_buf, unsigned* __restrict__ m, int E) {
    int idx = blockIdx.x * blockDim.x + threadIdx.x;
    if (idx >= E * HEADS) return;
    int e = idx >> 2, h = idx & 3;
    int s = src[e], d = dst[e];
    float v = el[s * HEADS + h] + er[d * HEADS + h];
    v = (v > 0.f) ? v : NEG_SLOPE * v;
    e_buf[idx] = v;
    atomicMax(&m[d * HEADS + h], flipf(v));
}

// ---------- 4. exp + segment sum ----------
__global__ __launch_bounds__(256) void edge_exp_kernel(
        const int* __restrict__ dst, const unsigned* __restrict__ m,
        float* __restrict__ e_buf, float* __restrict__ denom, int E) {
    int idx = blockIdx.x * blockDim.x + threadIdx.x;
    if (idx >= E * HEADS) return;
    int e = idx >> 2, h = idx & 3;
    int d = dst[e];
    float mx = unflipf(m[d * HEADS + h]);
    float ex = __expf(e_buf[idx] - mx);
    e_buf[idx] = ex;
    atomicAdd(&denom[d * HEADS + h], ex);
}

// ---------- 5. aggregate: out[n,d] = 0.25 * sum_h sum_e alpha * feat[src,h,d] ----------
// one wave per edge; lane = output dim d; 64 atomics per edge (head-sum in regs)
__global__ __launch_bounds__(256) void aggregate_kernel(
        const float* __restrict__ feat, const float* __restrict__ e_buf,
        const float* __restrict__ denom,
        const int* __restrict__ src, const int* __restrict__ dst,
        float* __restrict__ out, int E) {
    int wid = (blockIdx.x * blockDim.x + threadIdx.x) >> 6;
    int lane = threadIdx.x & 63;
    if (wid >= E) return;
    int s = src[wid], d = dst[wid];
    float4 ex4 = ((const float4*)e_buf)[wid];
    float4 dn4 = ((const float4*)denom)[d];
    float a0 = ex4.x / dn4.x;
    float a1 = ex4.y / dn4.y;
    float a2 = ex4.z / dn4.z;
    float a3 = ex4.w / dn4.w;
    const float* fr = feat + s * (HEADS * HID);
    float v = a0 * fr[lane] + a1 * fr[HID + lane] + a2 * fr[2 * HID + lane] + a3 * fr[3 * HID + lane];
    atomicAdd(&out[d * HID + lane], 0.25f * v);
}

extern "C" void kernel_launch(void* const* d_in, const int* in_sizes, int n_in,
                              void* d_out, int out_size, void* d_ws, size_t ws_size,
                              hipStream_t stream) {
    const float* x      = (const float*)d_in[0];
    const float* W      = (const float*)d_in[1];
    const float* attn_l = (const float*)d_in[2];
    const float* attn_r = (const float*)d_in[3];
    const int*   src    = (const int*)d_in[4];
    const int*   dst    = (const int*)d_in[5];
    float* out = (float*)d_out;

    const int N = in_sizes[0] / IN_DIM;   // 50000
    const int E = in_sizes[4];            // 800000

    // workspace layout (all 16B-aligned)
    float*    feat  = (float*)d_ws;                      // N*256
    float*    el    = feat + (size_t)N * IN_DIM;         // N*4
    float*    er    = el + (size_t)N * HEADS;            // N*4
    float*    e_buf = er + (size_t)N * HEADS;            // E*4
    unsigned* m     = (unsigned*)(e_buf + (size_t)E * HEADS); // N*4
    float*    denom = (float*)(m + (size_t)N * HEADS);   // N*4

    // zero-init accumulators (harness poisons ws/out with 0xAA)
    hipMemsetAsync(out, 0, (size_t)out_size * sizeof(float), stream);
    hipMemsetAsync(m, 0, (size_t)N * HEADS * sizeof(unsigned), stream);  // 0 == flip(< -inf)
    hipMemsetAsync(denom, 0, (size_t)N * HEADS * sizeof(float), stream);

    // 1. GEMM
    dim3 ggrid((N + TM - 1) / TM, (HEADS * HID) / TN);
    gemm_kernel<<<ggrid, 256, 0, stream>>>(x, W, feat, N);

    // 2. el/er
    int elr_blocks = (N * 64 + 255) / 256;
    elr_kernel<<<elr_blocks, 256, 0, stream>>>(feat, attn_l, attn_r, el, er, N);

    // 3. edge scores + segment max
    int ea_blocks = (E * HEADS + 255) / 256;
    edge_score_kernel<<<ea_blocks, 256, 0, stream>>>(el, er, src, dst, e_buf, m, E);

    // 4. exp + denom
    edge_exp_kernel<<<ea_blocks, 256, 0, stream>>>(dst, m, e_buf, denom, E);

    // 5. aggregate
    int agg_blocks = ((size_t)E * 64 + 255) / 256;
    aggregate_kernel<<<agg_blocks, 256, 0, stream>>>(feat, e_buf, denom, src, dst, out, E);
}